// Round 6
// baseline (478.996 us; speedup 1.0000x reference)
//
#include <hip/hip_runtime.h>

#define N_USERS 200000
#define N_ITEMS 100000
#define N_NODES 300000
#define DIM 64
#define N_INTER 1000000
#define N_EDGES (2 * N_INTER)

#define BSHIFT 10                      // 1024 nodes per bucket
#define BNODES (1 << BSHIFT)
#define NBUCKET ((N_NODES + BNODES - 1) >> BSHIFT)   // 293
#define TILE 4096                      // interactions per block in hist/place
#define NBLK_P ((N_INTER + TILE - 1) / TILE)          // 245

#define NPW 8                          // nodes (rows) per wave in gather
#define NWAVE ((N_NODES + NPW - 1) / NPW)             // 37500
#define GATHER_THREADS (NWAVE * 64)                   // 2,400,000

typedef unsigned short bf16_t;
typedef unsigned int u32;

static __device__ __forceinline__ bf16_t f2bf(float f) {
    union { float f; u32 u; } v; v.f = f;
    u32 r = v.u + 0x7FFFu + ((v.u >> 16) & 1u);
    return (bf16_t)(r >> 16);
}
static __device__ __forceinline__ float bf2f(bf16_t h) {
    union { u32 u; float f; } v; v.u = ((u32)h) << 16;
    return v.f;
}
static __device__ __forceinline__ float bflo(u32 v) {   // low bf16 of a packed dword
    union { u32 u; float f; } x; x.u = v << 16; return x.f;
}
static __device__ __forceinline__ float bfhi(u32 v) {   // high bf16 of a packed dword
    union { u32 u; float f; } x; x.u = v & 0xFFFF0000u; return x.f;
}
static __device__ __forceinline__ u32 pack_bf16(float lo, float hi) {   // RNE, = f2bf pair
    u32 r;
    asm("v_cvt_pk_bf16_f32 %0, %1, %2" : "=v"(r) : "v"(lo), "v"(hi));
    return r;
}

// ---------------- 1. bucket histogram (LDS, then one merge per bucket) ----------------
__global__ void hist_kernel(const int* __restrict__ uid, const int* __restrict__ iid,
                            u32* __restrict__ bucket_count) {
    __shared__ u32 h[NBUCKET];
    int t = threadIdx.x;
    for (int i = t; i < NBUCKET; i += 256) h[i] = 0;
    __syncthreads();
    int base = blockIdx.x * TILE;
    int end = base + TILE; if (end > N_INTER) end = N_INTER;
    for (int k = base + t; k < end; k += 256) {
        int u = uid[k];
        int it = N_USERS + iid[k];
        atomicAdd(&h[it >> BSHIFT], 1u);   // edge u->it lands in it's bucket
        atomicAdd(&h[u >> BSHIFT], 1u);    // edge it->u lands in u's bucket
    }
    __syncthreads();
    for (int i = t; i < NBUCKET; i += 256)
        if (h[i]) atomicAdd(&bucket_count[i], h[i]);
}

// ---------------- 2. scan bucket counts -> bstart, init cursors ----------------
__global__ void scan_kernel(const u32* __restrict__ bucket_count, u32* __restrict__ bstart,
                            u32* __restrict__ bucket_cursor, u32* __restrict__ rowptr) {
    __shared__ u32 buf[2][512];
    int t = threadIdx.x;  // 512 threads
    u32 v0 = (t < NBUCKET) ? bucket_count[t] : 0u;
    buf[0][t] = v0;
    __syncthreads();
    int s = 0;
    for (int off = 1; off < 512; off <<= 1) {
        u32 v = buf[s][t];
        if (t >= off) v += buf[s][t - off];
        buf[1 - s][t] = v;
        __syncthreads();
        s = 1 - s;
    }
    if (t < NBUCKET) {
        u32 excl = buf[s][t] - v0;
        bstart[t] = excl;
        bucket_cursor[t] = excl;
    }
    if (t == 0) {
        bstart[NBUCKET] = N_EDGES;
        rowptr[N_NODES] = N_EDGES;
    }
}

// ---------------- 3. place: exact per-(block,bucket) reservations ----------------
// entry = (local_dst << 19) | src   (src < 2^19, local_dst < 1024 -> bits 19..28)
__global__ void place_kernel(const int* __restrict__ uid, const int* __restrict__ iid,
                             u32* __restrict__ bucket_cursor, u32* __restrict__ bdata) {
    __shared__ u32 h[NBUCKET];      // pass1: counts; pass2: local cursor
    __shared__ u32 basesh[NBUCKET]; // reserved global base per bucket
    int t = threadIdx.x;
    for (int i = t; i < NBUCKET; i += 256) h[i] = 0;
    __syncthreads();
    int base = blockIdx.x * TILE;
    int end = base + TILE; if (end > N_INTER) end = N_INTER;
    // pass 1: local histogram
    for (int k = base + t; k < end; k += 256) {
        int u = uid[k];
        int it = N_USERS + iid[k];
        atomicAdd(&h[it >> BSHIFT], 1u);
        atomicAdd(&h[u >> BSHIFT], 1u);
    }
    __syncthreads();
    // reserve ranges
    for (int i = t; i < NBUCKET; i += 256) {
        u32 c = h[i];
        basesh[i] = c ? atomicAdd(&bucket_cursor[i], c) : 0u;
        h[i] = 0;
    }
    __syncthreads();
    // pass 2: place
    for (int k = base + t; k < end; k += 256) {
        int u = uid[k];
        int it = N_USERS + iid[k];
        {
            int b = it >> BSHIFT;
            u32 pos = basesh[b] + atomicAdd(&h[b], 1u);
            bdata[pos] = (((u32)(it & (BNODES - 1))) << 19) | (u32)u;
        }
        {
            int b = u >> BSHIFT;
            u32 pos = basesh[b] + atomicAdd(&h[b], 1u);
            bdata[pos] = (((u32)(u & (BNODES - 1))) << 19) | (u32)it;
        }
    }
}

// ---------------- 4. per-bucket CSR finalize: rowptr, dinv, col ----------------
__global__ void csr_kernel(const u32* __restrict__ bstart, const u32* __restrict__ bdata,
                           u32* __restrict__ rowptr, float* __restrict__ dinv,
                           int* __restrict__ col) {
    __shared__ u32 cnt[BNODES];
    __shared__ u32 sb[2][BNODES];
    __shared__ u32 cur[BNODES];
    int b = blockIdx.x;
    int t = threadIdx.x;               // 256 threads
    int nbase = b << BSHIFT;
    u32 bs = bstart[b], be = bstart[b + 1];
    u32 m = be - bs;

    #pragma unroll
    for (int j = 0; j < 4; ++j) cnt[t + j * 256] = 0;
    __syncthreads();
    // pass A: count per local node
    for (u32 e = t; e < m; e += 256) {
        u32 v = bdata[bs + e];
        atomicAdd(&cnt[v >> 19], 1u);
    }
    __syncthreads();
    // inclusive scan of 1024 (Hillis-Steele, 4 elems/thread)
    #pragma unroll
    for (int j = 0; j < 4; ++j) sb[0][t + j * 256] = cnt[t + j * 256];
    __syncthreads();
    int s = 0;
    for (int off = 1; off < BNODES; off <<= 1) {
        #pragma unroll
        for (int j = 0; j < 4; ++j) {
            int idx = t + j * 256;
            u32 v = sb[s][idx];
            if (idx >= off) v += sb[s][idx - off];
            sb[1 - s][idx] = v;
        }
        __syncthreads();
        s = 1 - s;
    }
    // rowptr, dinv, cursors
    #pragma unroll
    for (int j = 0; j < 4; ++j) {
        int idx = t + j * 256;
        int node = nbase + idx;
        u32 c = cnt[idx];
        u32 excl = sb[s][idx] - c;
        cur[idx] = excl;
        if (node < N_NODES) {
            rowptr[node] = bs + excl;
            dinv[node] = (c > 0) ? rsqrtf((float)c) : 0.0f;
        }
    }
    __syncthreads();
    // pass B: place col entries into contiguous [bs, be)
    for (u32 e = t; e < m; e += 256) {
        u32 v = bdata[bs + e];
        u32 ln = v >> 19;
        u32 pos = atomicAdd(&cur[ln], 1u);
        col[bs + pos] = (int)(v & 0x7FFFFu);
    }
}

// ---------------- 5. edge records: (src, dinv[src]) ----------------
__global__ void ecol_kernel(const int* __restrict__ col, const float* __restrict__ dinv,
                            int2* __restrict__ ecol) {
    int e = blockIdx.x * blockDim.x + threadIdx.x;
    if (e < N_EDGES) {
        int s = col[e];
        ecol[e] = make_int2(s, __float_as_int(dinv[s]));
    }
}

// ---------------- init: fp32 inputs -> bf16 layer-0 buffer ----------------
__global__ void init_kernel(const float4* __restrict__ ue, const float4* __restrict__ ie,
                            ushort4* __restrict__ cur) {
    int idx = blockIdx.x * blockDim.x + threadIdx.x;
    if (idx < N_NODES * 16) {
        float4 v = (idx < N_USERS * 16) ? ue[idx] : ie[idx - N_USERS * 16];
        ushort4 h;
        h.x = f2bf(v.x); h.y = f2bf(v.y); h.z = f2bf(v.z); h.w = f2bf(v.w);
        cur[idx] = h;
    }
}

// ---------------- gather SpMM: quad-row per wave, scalar edge records ----------------
// One wave owns an 8-row strip, processed as TWO quads of 4 rows. Lane layout:
// qid = lane>>4 selects the row within the quad, c = lane&15 the u64 column
// (4 bf16 cols). Per step: 4 scalar s_load_dwordx2 edge records (uniform
// indices, K$ hits) + ONE wave64 dwordx2 gather covering 512B = 4 edges
// (half R5's gather instructions, half the serial chain depth, 4 independent
// acc chains). (src,w) selected per-lane from the 4 SGPR records by a cndmask
// tree. Tail slots clamp to a valid edge with w=0 (all loads in-bounds).
__global__ void gather_kernel(const u32* __restrict__ rowptr, const int2* __restrict__ ecol,
                              const float* __restrict__ dinv,
                              const uint2* __restrict__ cur, uint2* __restrict__ nxt) {
    int wid = (blockIdx.x * blockDim.x + threadIdx.x) >> 6;
    int lane = threadIdx.x & 63;
    int n0 = __builtin_amdgcn_readfirstlane(wid * NPW);
    if (n0 >= N_NODES) return;
    u32 rp[NPW + 1];
    #pragma unroll
    for (int i = 0; i <= NPW; ++i) rp[i] = rowptr[n0 + i];   // uniform -> s_loads
    u32 qid = (u32)(lane >> 4);
    u32 c = (u32)(lane & 15);
    #pragma unroll
    for (int pr = 0; pr < NPW; pr += 4) {
        u32 rs0 = rp[pr],     l0 = rp[pr + 1] - rs0;
        u32 rs1 = rp[pr + 1], l1 = rp[pr + 2] - rs1;
        u32 rs2 = rp[pr + 2], l2 = rp[pr + 3] - rs2;
        u32 rs3 = rp[pr + 3], l3 = rp[pr + 4] - rs3;
        u32 m01 = l0 > l1 ? l0 : l1, m23 = l2 > l3 ? l2 : l3;
        u32 mx = m01 > m23 ? m01 : m23;
        u32 mylen = (qid & 2u) ? ((qid & 1u) ? l3 : l2) : ((qid & 1u) ? l1 : l0);
        float a0 = 0.0f, a1 = 0.0f, a2 = 0.0f, a3 = 0.0f;
        for (u32 p = 0; p < mx; p += 2) {
            #pragma unroll
            for (int u2 = 0; u2 < 2; ++u2) {
                u32 st = p + (u32)u2;
                u32 i0 = rs0 + st; if (i0 >= (u32)N_EDGES) i0 = N_EDGES - 1u;
                u32 i1 = rs1 + st; if (i1 >= (u32)N_EDGES) i1 = N_EDGES - 1u;
                u32 i2 = rs2 + st; if (i2 >= (u32)N_EDGES) i2 = N_EDGES - 1u;
                u32 i3 = rs3 + st; if (i3 >= (u32)N_EDGES) i3 = N_EDGES - 1u;
                i0 = __builtin_amdgcn_readfirstlane((int)i0);
                i1 = __builtin_amdgcn_readfirstlane((int)i1);
                i2 = __builtin_amdgcn_readfirstlane((int)i2);
                i3 = __builtin_amdgcn_readfirstlane((int)i3);
                int2 e0 = ecol[i0];                  // uniform -> s_load_dwordx2
                int2 e1 = ecol[i1];
                int2 e2 = ecol[i2];
                int2 e3 = ecol[i3];
                u32 srow = (qid & 2u) ? ((qid & 1u) ? (u32)e3.x : (u32)e2.x)
                                      : ((qid & 1u) ? (u32)e1.x : (u32)e0.x);
                u32 wsel = (qid & 2u) ? ((qid & 1u) ? (u32)e3.y : (u32)e2.y)
                                      : ((qid & 1u) ? (u32)e1.y : (u32)e0.y);
                float wf = __uint_as_float((st < mylen) ? wsel : 0u);
                uint2 v = cur[(srow << 4) + c];      // 512B wave64 gather, 4 rows
                a0 += wf * bflo(v.x);
                a1 += wf * bfhi(v.x);
                a2 += wf * bflo(v.y);
                a3 += wf * bfhi(v.y);
            }
        }
        u32 myrow = (u32)(n0 + pr) + qid;
        float sc = dinv[myrow];
        nxt[(myrow << 4) + c] = make_uint2(pack_bf16(sc * a0, sc * a1),
                                           pack_bf16(sc * a2, sc * a3));
    }
}

// ---------------- layer-3 gather fused with final combine ----------------
__global__ void gather_final_kernel(const u32* __restrict__ rowptr, const int2* __restrict__ ecol,
                                    const float* __restrict__ dinv,
                                    const uint2* __restrict__ b1, const uint2* __restrict__ b2,
                                    const float4* __restrict__ ue, const float4* __restrict__ ie,
                                    float4* __restrict__ out) {
    int wid = (blockIdx.x * blockDim.x + threadIdx.x) >> 6;
    int lane = threadIdx.x & 63;
    int n0 = __builtin_amdgcn_readfirstlane(wid * NPW);
    if (n0 >= N_NODES) return;
    u32 rp[NPW + 1];
    #pragma unroll
    for (int i = 0; i <= NPW; ++i) rp[i] = rowptr[n0 + i];
    u32 qid = (u32)(lane >> 4);
    u32 c = (u32)(lane & 15);
    #pragma unroll
    for (int pr = 0; pr < NPW; pr += 4) {
        u32 rs0 = rp[pr],     l0 = rp[pr + 1] - rs0;
        u32 rs1 = rp[pr + 1], l1 = rp[pr + 2] - rs1;
        u32 rs2 = rp[pr + 2], l2 = rp[pr + 3] - rs2;
        u32 rs3 = rp[pr + 3], l3 = rp[pr + 4] - rs3;
        u32 m01 = l0 > l1 ? l0 : l1, m23 = l2 > l3 ? l2 : l3;
        u32 mx = m01 > m23 ? m01 : m23;
        u32 mylen = (qid & 2u) ? ((qid & 1u) ? l3 : l2) : ((qid & 1u) ? l1 : l0);
        float a0 = 0.0f, a1 = 0.0f, a2 = 0.0f, a3 = 0.0f;
        for (u32 p = 0; p < mx; p += 2) {
            #pragma unroll
            for (int u2 = 0; u2 < 2; ++u2) {
                u32 st = p + (u32)u2;
                u32 i0 = rs0 + st; if (i0 >= (u32)N_EDGES) i0 = N_EDGES - 1u;
                u32 i1 = rs1 + st; if (i1 >= (u32)N_EDGES) i1 = N_EDGES - 1u;
                u32 i2 = rs2 + st; if (i2 >= (u32)N_EDGES) i2 = N_EDGES - 1u;
                u32 i3 = rs3 + st; if (i3 >= (u32)N_EDGES) i3 = N_EDGES - 1u;
                i0 = __builtin_amdgcn_readfirstlane((int)i0);
                i1 = __builtin_amdgcn_readfirstlane((int)i1);
                i2 = __builtin_amdgcn_readfirstlane((int)i2);
                i3 = __builtin_amdgcn_readfirstlane((int)i3);
                int2 e0 = ecol[i0];
                int2 e1 = ecol[i1];
                int2 e2 = ecol[i2];
                int2 e3 = ecol[i3];
                u32 srow = (qid & 2u) ? ((qid & 1u) ? (u32)e3.x : (u32)e2.x)
                                      : ((qid & 1u) ? (u32)e1.x : (u32)e0.x);
                u32 wsel = (qid & 2u) ? ((qid & 1u) ? (u32)e3.y : (u32)e2.y)
                                      : ((qid & 1u) ? (u32)e1.y : (u32)e0.y);
                float wf = __uint_as_float((st < mylen) ? wsel : 0u);
                uint2 v = b2[(srow << 4) + c];
                a0 += wf * bflo(v.x);
                a1 += wf * bfhi(v.x);
                a2 += wf * bflo(v.y);
                a3 += wf * bfhi(v.y);
            }
        }
        u32 myrow = (u32)(n0 + pr) + qid;
        float sc = dinv[myrow];
        u32 o = (myrow << 4) + c;
        uint2 v1 = b1[o], v2 = b2[o];
        float4 e0v = (myrow < (u32)N_USERS) ? ue[o] : ie[o - ((u32)N_USERS << 4)];
        float4 ov;
        ov.x = (e0v.x + bflo(v1.x) + bflo(v2.x) + sc * a0) * 0.25f;
        ov.y = (e0v.y + bfhi(v1.x) + bfhi(v2.x) + sc * a1) * 0.25f;
        ov.z = (e0v.z + bflo(v1.y) + bflo(v2.y) + sc * a2) * 0.25f;
        ov.w = (e0v.w + bfhi(v1.y) + bfhi(v2.y) + sc * a3) * 0.25f;
        out[o] = ov;
    }
}

extern "C" void kernel_launch(void* const* d_in, const int* in_sizes, int n_in,
                              void* d_out, int out_size, void* d_ws, size_t ws_size,
                              hipStream_t stream) {
    const float* ue = (const float*)d_in[0];
    const float* ie = (const float*)d_in[1];
    const int* uid = (const int*)d_in[2];
    const int* iid = (const int*)d_in[3];
    float* out = (float*)d_out;

    char* ws = (char*)d_ws;
    size_t off = 0;
    auto alloc = [&](size_t bytes) { char* p = ws + off; off = (off + bytes + 255) & ~(size_t)255; return p; };
    u32*    bucket_count  = (u32*)alloc((size_t)NBUCKET * 4);
    u32*    bstart        = (u32*)alloc((size_t)(NBUCKET + 1) * 4);
    u32*    bucket_cursor = (u32*)alloc((size_t)NBUCKET * 4);
    u32*    rowptr        = (u32*)alloc((size_t)(N_NODES + 1) * 4);
    float*  dinv          = (float*)alloc((size_t)N_NODES * 4);
    u32*    bdata         = (u32*)alloc((size_t)N_EDGES * 4);         // 8 MB
    int*    col           = (int*)alloc((size_t)N_EDGES * 4);         // 8 MB
    int2*   ecol          = (int2*)alloc((size_t)N_EDGES * 8);        // 16 MB
    bf16_t* buf0          = (bf16_t*)alloc((size_t)N_NODES * DIM * 2);
    bf16_t* buf1          = (bf16_t*)alloc((size_t)N_NODES * DIM * 2);
    bf16_t* buf2          = (bf16_t*)alloc((size_t)N_NODES * DIM * 2);

    // --- CSR build: exact-reservation bucketed, line-friendly writes throughout ---
    hipMemsetAsync(bucket_count, 0, (size_t)NBUCKET * 4, stream);
    hist_kernel<<<NBLK_P, 256, 0, stream>>>(uid, iid, bucket_count);
    scan_kernel<<<1, 512, 0, stream>>>(bucket_count, bstart, bucket_cursor, rowptr);
    place_kernel<<<NBLK_P, 256, 0, stream>>>(uid, iid, bucket_cursor, bdata);
    csr_kernel<<<NBUCKET, 256, 0, stream>>>(bstart, bdata, rowptr, dinv, col);
    ecol_kernel<<<(N_EDGES + 255) / 256, 256, 0, stream>>>(col, dinv, ecol);

    // --- init (fp32 -> bf16 layer 0) ---
    init_kernel<<<(N_NODES * 16 + 255) / 256, 256, 0, stream>>>(
        (const float4*)ue, (const float4*)ie, (ushort4*)buf0);

    // --- layers 1,2 gather; layer 3 fused with final combine ---
    gather_kernel<<<(GATHER_THREADS + 255) / 256, 256, 0, stream>>>(
        rowptr, ecol, dinv, (const uint2*)buf0, (uint2*)buf1);
    gather_kernel<<<(GATHER_THREADS + 255) / 256, 256, 0, stream>>>(
        rowptr, ecol, dinv, (const uint2*)buf1, (uint2*)buf2);
    gather_final_kernel<<<(GATHER_THREADS + 255) / 256, 256, 0, stream>>>(
        rowptr, ecol, dinv, (const uint2*)buf1, (const uint2*)buf2,
        (const float4*)ue, (const float4*)ie, (float4*)out);
}

// Round 7
// 423.709 us; speedup vs baseline: 1.1305x; 1.1305x over previous
//
#include <hip/hip_runtime.h>

#define N_USERS 200000
#define N_ITEMS 100000
#define N_NODES 300000
#define DIM 64
#define N_INTER 1000000
#define N_EDGES (2 * N_INTER)

#define BSHIFT 9                       // 512 nodes per bucket
#define BNODES (1 << BSHIFT)
#define NBUCKET ((N_NODES + BNODES - 1) >> BSHIFT)   // 586
#define TILE 2048                      // interactions per block in hist/place
#define NBLK_P ((N_INTER + TILE - 1) / TILE)          // 489

#define NPW 8                          // nodes (rows) per wave in gather
#define NWAVE ((N_NODES + NPW - 1) / NPW)             // 37500
#define GATHER_THREADS (NWAVE * 64)                   // 2,400,000

typedef unsigned short bf16_t;
typedef unsigned int u32;

static __device__ __forceinline__ bf16_t f2bf(float f) {
    union { float f; u32 u; } v; v.f = f;
    u32 r = v.u + 0x7FFFu + ((v.u >> 16) & 1u);
    return (bf16_t)(r >> 16);
}
static __device__ __forceinline__ float bf2f(bf16_t h) {
    union { u32 u; float f; } v; v.u = ((u32)h) << 16;
    return v.f;
}
static __device__ __forceinline__ float bflo(u32 v) {   // low bf16 of a packed dword
    union { u32 u; float f; } x; x.u = v << 16; return x.f;
}
static __device__ __forceinline__ float bfhi(u32 v) {   // high bf16 of a packed dword
    union { u32 u; float f; } x; x.u = v & 0xFFFF0000u; return x.f;
}
static __device__ __forceinline__ u32 pack_bf16(float lo, float hi) {   // RNE, = f2bf pair
    u32 r;
    asm("v_cvt_pk_bf16_f32 %0, %1, %2" : "=v"(r) : "v"(lo), "v"(hi));
    return r;
}

// ---------------- 1. bucket histogram; also stores per-block histogram ----------------
__global__ void hist_kernel(const int* __restrict__ uid, const int* __restrict__ iid,
                            u32* __restrict__ bucket_count, u32* __restrict__ bhist) {
    __shared__ u32 h[NBUCKET];
    int t = threadIdx.x;
    for (int i = t; i < NBUCKET; i += 256) h[i] = 0;
    __syncthreads();
    int base = blockIdx.x * TILE;
    int end = base + TILE; if (end > N_INTER) end = N_INTER;
    for (int k = base + t; k < end; k += 256) {
        int u = uid[k];
        int it = N_USERS + iid[k];
        atomicAdd(&h[it >> BSHIFT], 1u);   // edge u->it lands in it's bucket
        atomicAdd(&h[u >> BSHIFT], 1u);    // edge it->u lands in u's bucket
    }
    __syncthreads();
    u32* bh = bhist + (size_t)blockIdx.x * NBUCKET;   // coalesced per-block row
    for (int i = t; i < NBUCKET; i += 256) {
        u32 c = h[i];
        bh[i] = c;
        if (c) atomicAdd(&bucket_count[i], c);
    }
}

// ---------------- 2. scan bucket counts -> bstart ----------------
__global__ void scan_kernel(const u32* __restrict__ bucket_count, u32* __restrict__ bstart,
                            u32* __restrict__ rowptr) {
    __shared__ u32 buf[2][1024];
    int t = threadIdx.x;  // 1024 threads
    u32 v0 = (t < NBUCKET) ? bucket_count[t] : 0u;
    buf[0][t] = v0;
    __syncthreads();
    int s = 0;
    for (int off = 1; off < 1024; off <<= 1) {
        u32 v = buf[s][t];
        if (t >= off) v += buf[s][t - off];
        buf[1 - s][t] = v;
        __syncthreads();
        s = 1 - s;
    }
    if (t < NBUCKET) bstart[t] = buf[s][t] - v0;
    if (t == 0) {
        bstart[NBUCKET] = N_EDGES;
        rowptr[N_NODES] = N_EDGES;
    }
}

// ---------------- 2b. per-(block,bucket) bases: scan bhist over blocks, in place ------
// One block per bucket; reads are strided (L2-hot, just written), writes same slots.
__global__ void base_kernel(const u32* __restrict__ bstart, u32* __restrict__ bhist) {
    __shared__ u32 buf[2][512];
    int bkt = blockIdx.x;
    int t = threadIdx.x;               // 512 threads >= NBLK_P
    u32 v0 = (t < NBLK_P) ? bhist[(size_t)t * NBUCKET + bkt] : 0u;
    buf[0][t] = v0;
    __syncthreads();
    int s = 0;
    for (int off = 1; off < 512; off <<= 1) {
        u32 v = buf[s][t];
        if (t >= off) v += buf[s][t - off];
        buf[1 - s][t] = v;
        __syncthreads();
        s = 1 - s;
    }
    if (t < NBLK_P)
        bhist[(size_t)t * NBUCKET + bkt] = bstart[bkt] + (buf[s][t] - v0);
}

// ---------------- 3. place: exact precomputed bases, single pass over input ----------
// entry = (local_dst << 19) | src   (src < 2^19, local_dst < 512 -> bits 19..27)
__global__ void place_kernel(const int* __restrict__ uid, const int* __restrict__ iid,
                             const u32* __restrict__ bhist, u32* __restrict__ bdata) {
    __shared__ u32 h[NBUCKET];      // local cursor
    __shared__ u32 basesh[NBUCKET]; // precomputed global base per bucket
    int t = threadIdx.x;
    const u32* bh = bhist + (size_t)blockIdx.x * NBUCKET;   // coalesced
    for (int i = t; i < NBUCKET; i += 256) {
        basesh[i] = bh[i];
        h[i] = 0;
    }
    __syncthreads();
    int base = blockIdx.x * TILE;
    int end = base + TILE; if (end > N_INTER) end = N_INTER;
    for (int k = base + t; k < end; k += 256) {
        int u = uid[k];
        int it = N_USERS + iid[k];
        {
            int b = it >> BSHIFT;
            u32 pos = basesh[b] + atomicAdd(&h[b], 1u);
            bdata[pos] = (((u32)(it & (BNODES - 1))) << 19) | (u32)u;
        }
        {
            int b = u >> BSHIFT;
            u32 pos = basesh[b] + atomicAdd(&h[b], 1u);
            bdata[pos] = (((u32)(u & (BNODES - 1))) << 19) | (u32)it;
        }
    }
}

// ---------------- 4. per-bucket CSR finalize: rowptr, dinv, col ----------------
__global__ void csr_kernel(const u32* __restrict__ bstart, const u32* __restrict__ bdata,
                           u32* __restrict__ rowptr, float* __restrict__ dinv,
                           int* __restrict__ col) {
    __shared__ u32 cnt[BNODES];
    __shared__ u32 sb[2][BNODES];
    __shared__ u32 cur[BNODES];
    int b = blockIdx.x;
    int t = threadIdx.x;               // 256 threads
    int nbase = b << BSHIFT;
    u32 bs = bstart[b], be = bstart[b + 1];
    u32 m = be - bs;

    #pragma unroll
    for (int j = 0; j < BNODES / 256; ++j) cnt[t + j * 256] = 0;
    __syncthreads();
    // pass A: count per local node
    for (u32 e = t; e < m; e += 256) {
        u32 v = bdata[bs + e];
        atomicAdd(&cnt[v >> 19], 1u);
    }
    __syncthreads();
    // inclusive scan of BNODES (Hillis-Steele, BNODES/256 elems/thread)
    #pragma unroll
    for (int j = 0; j < BNODES / 256; ++j) sb[0][t + j * 256] = cnt[t + j * 256];
    __syncthreads();
    int s = 0;
    for (int off = 1; off < BNODES; off <<= 1) {
        #pragma unroll
        for (int j = 0; j < BNODES / 256; ++j) {
            int idx = t + j * 256;
            u32 v = sb[s][idx];
            if (idx >= off) v += sb[s][idx - off];
            sb[1 - s][idx] = v;
        }
        __syncthreads();
        s = 1 - s;
    }
    // rowptr, dinv, cursors
    #pragma unroll
    for (int j = 0; j < BNODES / 256; ++j) {
        int idx = t + j * 256;
        int node = nbase + idx;
        u32 c = cnt[idx];
        u32 excl = sb[s][idx] - c;
        cur[idx] = excl;
        if (node < N_NODES) {
            rowptr[node] = bs + excl;
            dinv[node] = (c > 0) ? rsqrtf((float)c) : 0.0f;
        }
    }
    __syncthreads();
    // pass B: place col entries into contiguous [bs, be)
    for (u32 e = t; e < m; e += 256) {
        u32 v = bdata[bs + e];
        u32 ln = v >> 19;
        u32 pos = atomicAdd(&cur[ln], 1u);
        col[bs + pos] = (int)(v & 0x7FFFFu);
    }
}

// ---------------- 5. edge records: (src, dinv[src]) ----------------
__global__ void ecol_kernel(const int* __restrict__ col, const float* __restrict__ dinv,
                            int2* __restrict__ ecol) {
    int e = blockIdx.x * blockDim.x + threadIdx.x;
    if (e < N_EDGES) {
        int s = col[e];
        ecol[e] = make_int2(s, __float_as_int(dinv[s]));
    }
}

// ---------------- init: fp32 inputs -> bf16 layer-0 buffer ----------------
__global__ void init_kernel(const float4* __restrict__ ue, const float4* __restrict__ ie,
                            ushort4* __restrict__ cur) {
    int idx = blockIdx.x * blockDim.x + threadIdx.x;
    if (idx < N_NODES * 16) {
        float4 v = (idx < N_USERS * 16) ? ue[idx] : ie[idx - N_USERS * 16];
        ushort4 h;
        h.x = f2bf(v.x); h.y = f2bf(v.y); h.z = f2bf(v.z); h.w = f2bf(v.w);
        cur[idx] = h;
    }
}

// ---------------- gather SpMM: row-pair per wave, scalar edge records (R5) ------------
// One wave owns an 8-row strip; rows are processed in PAIRS: lanes 0-31
// accumulate row 2r (2 bf16 cols/lane via one u32), lanes 32-63 row 2r+1.
// Edge records come from SCALAR loads (uniform index -> s_load_dwordx2,
// scalar-cache hits), so the only vector-memory op in the loop is the gather
// itself: ONE wave64 dword load covers BOTH rows' 128B and the two acc chains
// double MLP. Inner loop unrolled x4 -> 4 gathers in flight/wave. Tail slots
// clamp the edge index to a valid edge (w=0), so all loads stay in-bounds.
__global__ void gather_kernel(const u32* __restrict__ rowptr, const int2* __restrict__ ecol,
                              const float* __restrict__ dinv,
                              const u32* __restrict__ cur, u32* __restrict__ nxt) {
    int wid = (blockIdx.x * blockDim.x + threadIdx.x) >> 6;
    int lane = threadIdx.x & 63;
    int n0 = __builtin_amdgcn_readfirstlane(wid * NPW);
    if (n0 >= N_NODES) return;
    u32 rp[NPW + 1];
    #pragma unroll
    for (int i = 0; i <= NPW; ++i) rp[i] = rowptr[n0 + i];   // uniform -> s_loads
    bool hi = (lane >> 5) != 0;
    u32 c = (u32)(lane & 31);
    #pragma unroll
    for (int pr = 0; pr < NPW; pr += 2) {
        u32 rsA = rp[pr],     lA = rp[pr + 1] - rp[pr];
        u32 rsB = rp[pr + 1], lB = rp[pr + 2] - rp[pr + 1];
        u32 mx = lA > lB ? lA : lB;
        float a0 = 0.0f, a1 = 0.0f;
        for (u32 p = 0; p < mx; p += 4) {
            #pragma unroll
            for (int q = 0; q < 4; ++q) {
                u32 st = p + (u32)q;
                u32 iA = rsA + st; if (iA >= (u32)N_EDGES) iA = N_EDGES - 1u;
                u32 iB = rsB + st; if (iB >= (u32)N_EDGES) iB = N_EDGES - 1u;
                iA = __builtin_amdgcn_readfirstlane((int)iA);
                iB = __builtin_amdgcn_readfirstlane((int)iB);
                int2 eA = ecol[iA];                    // uniform -> s_load_dwordx2
                int2 eB = ecol[iB];
                u32 wAu = (st < lA) ? (u32)eA.y : 0u;  // uniform -> s_cselect
                u32 wBu = (st < lB) ? (u32)eB.y : 0u;
                u32 srow = hi ? (u32)eB.x : (u32)eA.x;           // v_cndmask
                float wf = __uint_as_float(hi ? wBu : wAu);       // v_cndmask
                u32 v = cur[(srow << 5) + c];
                a0 += wf * bflo(v);
                a1 += wf * bfhi(v);
            }
        }
        float sc = hi ? dinv[n0 + pr + 1] : dinv[n0 + pr];        // uniform loads + sel
        u32 orow = (((u32)(n0 + pr) + (hi ? 1u : 0u)) << 5) + c;  // 2 rows = 256B store
        nxt[orow] = pack_bf16(sc * a0, sc * a1);
    }
}

// ---------------- layer-3 gather fused with final combine ----------------
__global__ void gather_final_kernel(const u32* __restrict__ rowptr, const int2* __restrict__ ecol,
                                    const float* __restrict__ dinv,
                                    const u32* __restrict__ b1, const u32* __restrict__ b2,
                                    const float* __restrict__ ue, const float* __restrict__ ie,
                                    float* __restrict__ out) {
    int wid = (blockIdx.x * blockDim.x + threadIdx.x) >> 6;
    int lane = threadIdx.x & 63;
    int n0 = __builtin_amdgcn_readfirstlane(wid * NPW);
    if (n0 >= N_NODES) return;
    u32 rp[NPW + 1];
    #pragma unroll
    for (int i = 0; i <= NPW; ++i) rp[i] = rowptr[n0 + i];
    bool hi = (lane >> 5) != 0;
    u32 c = (u32)(lane & 31);
    #pragma unroll
    for (int pr = 0; pr < NPW; pr += 2) {
        u32 rsA = rp[pr],     lA = rp[pr + 1] - rp[pr];
        u32 rsB = rp[pr + 1], lB = rp[pr + 2] - rp[pr + 1];
        u32 mx = lA > lB ? lA : lB;
        float a0 = 0.0f, a1 = 0.0f;
        for (u32 p = 0; p < mx; p += 4) {
            #pragma unroll
            for (int q = 0; q < 4; ++q) {
                u32 st = p + (u32)q;
                u32 iA = rsA + st; if (iA >= (u32)N_EDGES) iA = N_EDGES - 1u;
                u32 iB = rsB + st; if (iB >= (u32)N_EDGES) iB = N_EDGES - 1u;
                iA = __builtin_amdgcn_readfirstlane((int)iA);
                iB = __builtin_amdgcn_readfirstlane((int)iB);
                int2 eA = ecol[iA];
                int2 eB = ecol[iB];
                u32 wAu = (st < lA) ? (u32)eA.y : 0u;
                u32 wBu = (st < lB) ? (u32)eB.y : 0u;
                u32 srow = hi ? (u32)eB.x : (u32)eA.x;
                float wf = __uint_as_float(hi ? wBu : wAu);
                u32 v = b2[(srow << 5) + c];
                a0 += wf * bflo(v);
                a1 += wf * bfhi(v);
            }
        }
        int n = n0 + pr + (hi ? 1 : 0);
        float sc = hi ? dinv[n0 + pr + 1] : dinv[n0 + pr];
        u32 o32 = (((u32)n) << 5) + c;
        u32 v1 = b1[o32], v2 = b2[o32];
        float2 e0 = (n < N_USERS) ? ((const float2*)ue)[o32]
                                  : ((const float2*)ie)[o32 - (u32)N_USERS * 32u];
        float ox = (e0.x + bflo(v1) + bflo(v2) + sc * a0) * 0.25f;
        float oy = (e0.y + bfhi(v1) + bfhi(v2) + sc * a1) * 0.25f;
        ((float2*)out)[o32] = make_float2(ox, oy);
    }
}

extern "C" void kernel_launch(void* const* d_in, const int* in_sizes, int n_in,
                              void* d_out, int out_size, void* d_ws, size_t ws_size,
                              hipStream_t stream) {
    const float* ue = (const float*)d_in[0];
    const float* ie = (const float*)d_in[1];
    const int* uid = (const int*)d_in[2];
    const int* iid = (const int*)d_in[3];
    float* out = (float*)d_out;

    char* ws = (char*)d_ws;
    size_t off = 0;
    auto alloc = [&](size_t bytes) { char* p = ws + off; off = (off + bytes + 255) & ~(size_t)255; return p; };
    u32*    bucket_count  = (u32*)alloc((size_t)NBUCKET * 4);
    u32*    bstart        = (u32*)alloc((size_t)(NBUCKET + 1) * 4);
    u32*    bhist         = (u32*)alloc((size_t)NBLK_P * NBUCKET * 4);  // 1.15 MB
    u32*    rowptr        = (u32*)alloc((size_t)(N_NODES + 1) * 4);
    float*  dinv          = (float*)alloc((size_t)N_NODES * 4);
    u32*    bdata         = (u32*)alloc((size_t)N_EDGES * 4);         // 8 MB
    int*    col           = (int*)alloc((size_t)N_EDGES * 4);         // 8 MB
    int2*   ecol          = (int2*)alloc((size_t)N_EDGES * 8);        // 16 MB
    bf16_t* buf0          = (bf16_t*)alloc((size_t)N_NODES * DIM * 2);
    bf16_t* buf1          = (bf16_t*)alloc((size_t)N_NODES * DIM * 2);
    bf16_t* buf2          = (bf16_t*)alloc((size_t)N_NODES * DIM * 2);

    // --- CSR build: exact-reservation bucketed, single-read place ---
    hipMemsetAsync(bucket_count, 0, (size_t)NBUCKET * 4, stream);
    hist_kernel<<<NBLK_P, 256, 0, stream>>>(uid, iid, bucket_count, bhist);
    scan_kernel<<<1, 1024, 0, stream>>>(bucket_count, bstart, rowptr);
    base_kernel<<<NBUCKET, 512, 0, stream>>>(bstart, bhist);
    place_kernel<<<NBLK_P, 256, 0, stream>>>(uid, iid, bhist, bdata);
    csr_kernel<<<NBUCKET, 256, 0, stream>>>(bstart, bdata, rowptr, dinv, col);
    ecol_kernel<<<(N_EDGES + 255) / 256, 256, 0, stream>>>(col, dinv, ecol);

    // --- init (fp32 -> bf16 layer 0) ---
    init_kernel<<<(N_NODES * 16 + 255) / 256, 256, 0, stream>>>(
        (const float4*)ue, (const float4*)ie, (ushort4*)buf0);

    // --- layers 1,2 gather; layer 3 fused with final combine ---
    gather_kernel<<<(GATHER_THREADS + 255) / 256, 256, 0, stream>>>(
        rowptr, ecol, dinv, (const u32*)buf0, (u32*)buf1);
    gather_kernel<<<(GATHER_THREADS + 255) / 256, 256, 0, stream>>>(
        rowptr, ecol, dinv, (const u32*)buf1, (u32*)buf2);
    gather_final_kernel<<<(GATHER_THREADS + 255) / 256, 256, 0, stream>>>(
        rowptr, ecol, dinv, (const u32*)buf1, (const u32*)buf2, ue, ie, out);
}